// Round 2
// baseline (744.694 us; speedup 1.0000x reference)
//
#include <hip/hip_runtime.h>
#include <math.h>

#define H 2048
#define G 6144   // 3*H
#define V 50257

// ---- workspace layout (float indices) ----
// [0, 2048)            h_new
// [2048, 2048+V)       logits
// fallback path (small ws):
//   [53248, 53376)     128 per-block max partials (K3)
//   [53376, 53504)     128 per-block sumexp partials (K3)
// fused path (large ws):
//   [53248, 53248+NB)  per-K2-block max partials
//   [59648, 59648+NB)  per-K2-block sumexp partials
#define WS_HNEW  0
#define WS_LOGIT 2048
#define WS_PMAX  53248
#define WS_PSUM  53376
#define NPART    128        // fallback partial blocks
#define NB2      6283       // ceil(V/8) — K2 block count
#define WS_PMAX2 53248
#define WS_PSUM2 59648      // 53248 + 6400 (padded)
#define WS_FUSED_END 66048  // 59648 + 6400 floats

typedef float f4 __attribute__((ext_vector_type(4)));

__device__ __forceinline__ float waveReduceSum(float v) {
  #pragma unroll
  for (int off = 32; off > 0; off >>= 1) v += __shfl_down(v, off, 64);
  return v;
}
__device__ __forceinline__ float waveReduceMax(float v) {
  #pragma unroll
  for (int off = 32; off > 0; off >>= 1) v = fmaxf(v, __shfl_down(v, off, 64));
  return v;
}
__device__ __forceinline__ float sigmoidf(float x) {
  return 1.f / (1.f + expf(-x));
}

// K1: fused GRU step, 2 waves per h-index.
// wave side 0: the three w_ih-row dots against relu(emb[token]);
// wave side 1: the three w_hh-row dots against hidden.
// Combine in smem; side-0 lane 0 does the gate math.
// Grid: H/2 = 1024 blocks x 256 threads (2 h-indices per block).
__global__ __launch_bounds__(256) void gru_kernel(
    const int* __restrict__ token, const float* __restrict__ hidden,
    const float* __restrict__ emb, const float* __restrict__ w_ih,
    const float* __restrict__ w_hh, const float* __restrict__ b_ih,
    const float* __restrict__ b_hh, float* __restrict__ ws,
    float* __restrict__ out) {
  const int wave = threadIdx.x >> 6;
  const int lane = threadIdx.x & 63;
  const int li   = wave >> 1;      // 0..1: which h-index in this block
  const int side = wave & 1;       // 0: input side (w_ih,x)  1: hidden side (w_hh,h)
  const int i = blockIdx.x * 2 + li;
  __shared__ float sums[2][2][3];  // [li][side][gate r,z,n]

  const f4* v4 = side ? (const f4*)hidden
                      : (const f4*)(emb + (size_t)token[0] * H);
  const float* wmat = side ? w_hh : w_ih;
  const f4* w_r = (const f4*)(wmat + (size_t)i * H);
  const f4* w_z = (const f4*)(wmat + (size_t)(H + i) * H);
  const f4* w_n = (const f4*)(wmat + (size_t)(2 * H + i) * H);

  float sr = 0.f, sz = 0.f, sn = 0.f;
  #pragma unroll
  for (int k = 0; k < 8; ++k) {
    const int idx = k * 64 + lane;
    f4 xv = v4[idx];
    if (!side) {  // wave-uniform branch: ReLU on the embedding vector
      xv.x = fmaxf(xv.x, 0.f); xv.y = fmaxf(xv.y, 0.f);
      xv.z = fmaxf(xv.z, 0.f); xv.w = fmaxf(xv.w, 0.f);
    }
    f4 a;
    a = w_r[idx]; sr += a.x*xv.x + a.y*xv.y + a.z*xv.z + a.w*xv.w;
    a = w_z[idx]; sz += a.x*xv.x + a.y*xv.y + a.z*xv.z + a.w*xv.w;
    a = w_n[idx]; sn += a.x*xv.x + a.y*xv.y + a.z*xv.z + a.w*xv.w;
  }
  sr = waveReduceSum(sr);
  sz = waveReduceSum(sz);
  sn = waveReduceSum(sn);
  if (lane == 0) {
    sums[li][side][0] = sr;
    sums[li][side][1] = sz;
    sums[li][side][2] = sn;
  }
  __syncthreads();
  if (side == 0 && lane == 0) {
    const float s_ir = sums[li][0][0], s_hr = sums[li][1][0];
    const float s_iz = sums[li][0][1], s_hz = sums[li][1][1];
    const float s_in = sums[li][0][2], s_hn = sums[li][1][2];
    const float r = sigmoidf(s_ir + b_ih[i] + s_hr + b_hh[i]);
    const float z = sigmoidf(s_iz + b_ih[H + i] + s_hz + b_hh[H + i]);
    const float n = tanhf(s_in + b_ih[2 * H + i] + r * (s_hn + b_hh[2 * H + i]));
    const float hn = (1.f - z) * n + z * hidden[i];
    ws[WS_HNEW + i] = hn;
    out[V + i] = hn;   // second output: new hidden state
  }
}

// K2: logits[v] = w_out[v,:] . h_new + b_out[v], 2 rows per wave, 8 per block.
// h slice lives in registers; NT loads keep the read-once 412 MB w_out stream
// from evicting the GRU weights out of L3.
// If write_partials != 0, also emits this block's (max, sumexp) softmax
// partial — no extra global reads (fuses old K3).
__global__ __launch_bounds__(256) void logits_kernel(
    const float* __restrict__ w_out, const float* __restrict__ b_out,
    float* __restrict__ ws, int write_partials) {
  const int wave = threadIdx.x >> 6;
  const int lane = threadIdx.x & 63;
  const int row0 = blockIdx.x * 8 + wave * 2;
  const int valid0 = (row0 < V);
  const int valid1 = (row0 + 1 < V);
  const int r0 = valid0 ? row0 : 0;       // clamped: loads always in-bounds
  const int r1 = valid1 ? row0 + 1 : 0;

  const f4* h4 = (const f4*)(ws + WS_HNEW);
  f4 hv[8];
  #pragma unroll
  for (int k = 0; k < 8; ++k) hv[k] = h4[k * 64 + lane];

  const f4* w0 = (const f4*)(w_out + (size_t)r0 * H);
  const f4* w1 = (const f4*)(w_out + (size_t)r1 * H);
  float s0 = 0.f, s1 = 0.f;
  #pragma unroll
  for (int k = 0; k < 8; ++k) {
    const int idx = k * 64 + lane;
    f4 a0 = __builtin_nontemporal_load(w0 + idx);
    f4 a1 = __builtin_nontemporal_load(w1 + idx);
    s0 += a0.x*hv[k].x + a0.y*hv[k].y + a0.z*hv[k].z + a0.w*hv[k].w;
    s1 += a1.x*hv[k].x + a1.y*hv[k].y + a1.z*hv[k].z + a1.w*hv[k].w;
  }
  s0 = waveReduceSum(s0);
  s1 = waveReduceSum(s1);

  __shared__ float lv[8];
  if (lane == 0) {
    const float l0 = s0 + b_out[r0];
    const float l1 = s1 + b_out[r1];
    lv[wave * 2]     = valid0 ? l0 : -INFINITY;
    lv[wave * 2 + 1] = valid1 ? l1 : -INFINITY;
    if (valid0) ws[WS_LOGIT + row0] = l0;
    if (valid1) ws[WS_LOGIT + row0 + 1] = l1;
  }
  if (!write_partials) return;
  __syncthreads();
  if (threadIdx.x == 0) {
    float m = -INFINITY;
    #pragma unroll
    for (int j = 0; j < 8; ++j) m = fmaxf(m, lv[j]);
    float s = 0.f;
    #pragma unroll
    for (int j = 0; j < 8; ++j) s += expf(lv[j] - m);  // exp(-inf - m) = 0
    ws[WS_PMAX2 + blockIdx.x] = m;
    ws[WS_PSUM2 + blockIdx.x] = s;
  }
}

// K4 (fused path): every block redundantly merges the NB per-K2-block
// partials (L2-resident, ~25 expf/thread) then writes its 256 outputs.
__global__ __launch_bounds__(256) void writeout_big_kernel(
    const float* __restrict__ ws, float* __restrict__ out, int nb) {
  __shared__ float sred[4];
  __shared__ float sM, sLse;
  const int wave = threadIdx.x >> 6;
  const int lane = threadIdx.x & 63;
  float m = -INFINITY;
  for (int j = threadIdx.x; j < nb; j += 256) m = fmaxf(m, ws[WS_PMAX2 + j]);
  m = waveReduceMax(m);
  if (lane == 0) sred[wave] = m;
  __syncthreads();
  if (threadIdx.x == 0)
    sM = fmaxf(fmaxf(sred[0], sred[1]), fmaxf(sred[2], sred[3]));
  __syncthreads();
  const float M = sM;
  float s = 0.f;
  for (int j = threadIdx.x; j < nb; j += 256)
    s += ws[WS_PSUM2 + j] * expf(ws[WS_PMAX2 + j] - M);
  s = waveReduceSum(s);
  __syncthreads();            // all reads of sred (max phase) done
  if (lane == 0) sred[wave] = s;
  __syncthreads();
  if (threadIdx.x == 0)
    sLse = M + logf(sred[0] + sred[1] + sred[2] + sred[3]);
  __syncthreads();
  const float lse = sLse;
  const int i = blockIdx.x * 256 + threadIdx.x;
  if (i < V) out[i] = ws[WS_LOGIT + i] - lse;
}

// ---- fallback path (small workspace): old K3 + K4 over NPART=128 ----
__global__ __launch_bounds__(256) void partial_kernel(float* __restrict__ ws) {
  __shared__ float sred[4];
  __shared__ float sbmax;
  const int wave = threadIdx.x >> 6;
  const int lane = threadIdx.x & 63;
  float m = -INFINITY;
  for (int i = blockIdx.x * 256 + threadIdx.x; i < V; i += NPART * 256)
    m = fmaxf(m, ws[WS_LOGIT + i]);
  m = waveReduceMax(m);
  if (lane == 0) sred[wave] = m;
  __syncthreads();
  if (threadIdx.x == 0)
    sbmax = fmaxf(fmaxf(sred[0], sred[1]), fmaxf(sred[2], sred[3]));
  __syncthreads();
  const float M = sbmax;
  float s = 0.f;
  for (int i = blockIdx.x * 256 + threadIdx.x; i < V; i += NPART * 256)
    s += expf(ws[WS_LOGIT + i] - M);
  s = waveReduceSum(s);
  __syncthreads();
  if (lane == 0) sred[wave] = s;
  __syncthreads();
  if (threadIdx.x == 0) {
    ws[WS_PMAX + blockIdx.x] = M;
    ws[WS_PSUM + blockIdx.x] = sred[0] + sred[1] + sred[2] + sred[3];
  }
}

__global__ __launch_bounds__(256) void writeout_kernel(
    const float* __restrict__ ws, float* __restrict__ out) {
  __shared__ float pm[NPART], psv[NPART];
  __shared__ float sM[2], sS[2];
  __shared__ float sLse;
  const int tid = threadIdx.x;
  if (tid < NPART) {
    pm[tid]  = ws[WS_PMAX + tid];
    psv[tid] = ws[WS_PSUM + tid];
  }
  __syncthreads();
  if (tid < NPART) {
    float m = waveReduceMax(pm[tid]);
    if ((tid & 63) == 0) sM[tid >> 6] = m;
  }
  __syncthreads();
  const float M = fmaxf(sM[0], sM[1]);
  if (tid < NPART) {
    float e = psv[tid] * expf(pm[tid] - M);
    e = waveReduceSum(e);
    if ((tid & 63) == 0) sS[tid >> 6] = e;
  }
  __syncthreads();
  if (tid == 0) sLse = M + logf(sS[0] + sS[1]);
  __syncthreads();
  const float lse = sLse;
  const int i = blockIdx.x * 256 + tid;
  if (i < V) out[i] = ws[WS_LOGIT + i] - lse;
}

extern "C" void kernel_launch(void* const* d_in, const int* in_sizes, int n_in,
                              void* d_out, int out_size, void* d_ws, size_t ws_size,
                              hipStream_t stream) {
  const int*   token  = (const int*)  d_in[0];
  const float* hidden = (const float*)d_in[1];
  const float* emb    = (const float*)d_in[2];
  const float* w_ih   = (const float*)d_in[3];
  const float* w_hh   = (const float*)d_in[4];
  const float* b_ih   = (const float*)d_in[5];
  const float* b_hh   = (const float*)d_in[6];
  const float* w_out  = (const float*)d_in[7];
  const float* b_out  = (const float*)d_in[8];
  float* out = (float*)d_out;
  float* ws  = (float*)d_ws;

  const int fused = (ws_size >= (size_t)WS_FUSED_END * sizeof(float));

  gru_kernel<<<H / 2, 256, 0, stream>>>(token, hidden, emb, w_ih, w_hh,
                                        b_ih, b_hh, ws, out);
  logits_kernel<<<NB2, 256, 0, stream>>>(w_out, b_out, ws, fused);
  if (fused) {
    writeout_big_kernel<<<(V + 255) / 256, 256, 0, stream>>>(ws, out, NB2);
  } else {
    partial_kernel<<<NPART, 256, 0, stream>>>(ws);
    writeout_kernel<<<(V + 255) / 256, 256, 0, stream>>>(ws, out);
  }
}